// Round 1
// baseline (2649.842 us; speedup 1.0000x reference)
//
#include <hip/hip_runtime.h>
#include <hip/hip_bf16.h>
#include <math.h>

// Sizes
#define BB 256
#define OBS 512
#define NA 64
#define MSG 2048
#define HID 1024
#define TAU 576       // OBS+NA
#define VD 8          // MSG/A
#define QN 16320      // (A-1)*NA
#define X2W 16896     // QN + NA + OBS
#define INW 3136      // 2*OBS+NA+MSG
#define PIW 2560      // OBS+MSG

// ---------------- tiled NT matmul: C[m,n] = act(sum_k X[m,k]*W[n,k] + bias[n]) --------
// X:(M,K) ldx, W:(N,K) ldw, C:(M,N) ldc.  ATOMIC: atomicAdd partial sums (bias ignored),
// split-K via blockIdx.z over kchunk ranges.
template<int ACT, bool ATOMIC>
__global__ __launch_bounds__(256)
void k_matmul(const float* __restrict__ X, int ldx,
              const float* __restrict__ W, int ldw,
              const float* __restrict__ bias,
              float* __restrict__ C, int ldc,
              int M, int N, int K, int kchunk)
{
  __shared__ float Xs[16][68];
  __shared__ float Ws[16][68];
  const int tid = threadIdx.x;
  const int tx = tid & 15, ty = tid >> 4;
  const int m0 = blockIdx.y * 64;
  const int n0 = blockIdx.x * 64;
  const int k0 = blockIdx.z * kchunk;
  const int k1 = min(K, k0 + kchunk);
  const int lk = tid & 15;
  const int lm = tid >> 4;
  float acc[4][4] = {};
  for (int kt = k0; kt < k1; kt += 16) {
#pragma unroll
    for (int r = 0; r < 4; ++r)
      Xs[lk][lm + 16 * r] = X[(size_t)(m0 + lm + 16 * r) * ldx + kt + lk];
#pragma unroll
    for (int r = 0; r < 4; ++r)
      Ws[lk][lm + 16 * r] = W[(size_t)(n0 + lm + 16 * r) * ldw + kt + lk];
    __syncthreads();
#pragma unroll
    for (int kk = 0; kk < 16; ++kk) {
      float xv[4], wv[4];
#pragma unroll
      for (int i = 0; i < 4; ++i) xv[i] = Xs[kk][ty * 4 + i];
#pragma unroll
      for (int j = 0; j < 4; ++j) wv[j] = Ws[kk][tx * 4 + j];
#pragma unroll
      for (int i = 0; i < 4; ++i)
#pragma unroll
        for (int j = 0; j < 4; ++j)
          acc[i][j] = fmaf(xv[i], wv[j], acc[i][j]);
    }
    __syncthreads();
  }
#pragma unroll
  for (int i = 0; i < 4; ++i) {
    const int m = m0 + ty * 4 + i;
#pragma unroll
    for (int j = 0; j < 4; ++j) {
      const int n = n0 + tx * 4 + j;
      if (ATOMIC) {
        atomicAdd(&C[(size_t)m * ldc + n], acc[i][j]);
      } else {
        float v = acc[i][j] + bias[n];
        if (ACT == 1) v = fmaxf(v, 0.f);
        C[(size_t)m * ldc + n] = v;
      }
    }
  }
}

// ---------------- GRU elementwise ----------------
__global__ __launch_bounds__(256)
void k_gru(const float* __restrict__ gi, const float* __restrict__ gh,
           const float* __restrict__ h_src, int ld_src,
           float* __restrict__ h_dst, int ld_dst)
{
  int idx = blockIdx.x * 256 + threadIdx.x;     // 256*1024
  int b = idx >> 10, j = idx & 1023;
  float ir = gi[b * 3072 + j];
  float iz = gi[b * 3072 + 1024 + j];
  float in_ = gi[b * 3072 + 2048 + j];
  float hr = gh[b * 3072 + j];
  float hz = gh[b * 3072 + 1024 + j];
  float hn = gh[b * 3072 + 2048 + j];
  float r = 1.f / (1.f + expf(-(ir + hr)));
  float z = 1.f / (1.f + expf(-(iz + hz)));
  float n = tanhf(in_ + r * hn);
  float h = h_src[(size_t)b * ld_src + j];
  h_dst[(size_t)b * ld_dst + j] = (1.f - z) * n + z * h;
}

// softmax over 64-wide rows of q (B,255,64), scatter through the transpose-reshape
// scramble directly into x2 (B rows of width 16896, fa part = first 16320 cols).
__global__ __launch_bounds__(256)
void k_softmax_scatter(const float* __restrict__ q, float* __restrict__ x2)
{
  int wid = blockIdx.x * 4 + (threadIdx.x >> 6);   // 0..65279
  int lane = threadIdx.x & 63;
  int b = wid / 255, p = wid % 255;
  float v = q[(size_t)b * QN + p * 64 + lane];
  float m = v;
#pragma unroll
  for (int s = 32; s; s >>= 1) m = fmaxf(m, __shfl_xor(m, s));
  float e = expf(v - m);
  float sum = e;
#pragma unroll
  for (int s = 32; s; s >>= 1) sum += __shfl_xor(sum, s);
  float r = e / sum;
  int flat = p * 16384 + b * 64 + lane;     // transpose(qs,(1,0,2)) flat index
  int bp = flat / QN;
  int j = flat - bp * QN;
  x2[(size_t)bp * X2W + j] = r;
}

// fill x2 tail: cols [16320,16384) = a_t, [16384,16896) = o_t  (from taus row)
__global__ __launch_bounds__(256)
void k_x2_tail(const float* __restrict__ taus_t, float* __restrict__ x2)
{
  int idx = blockIdx.x * 256 + threadIdx.x;   // 256*576
  int b = idx / TAU, c = idx % TAU;
  if (c < 64)
    x2[(size_t)b * X2W + QN + c] = taus_t[b * TAU + OBS + c];
  else
    x2[(size_t)b * X2W + QN + 64 + (c - 64)] = taus_t[b * TAU + (c - 64)];
}

// pi input concat during rollout: [o_t (from taus), prev_msg (inputs cols 1088..)]
__global__ __launch_bounds__(256)
void k_concat_pi_loop(const float* __restrict__ taus_t, const float* __restrict__ in,
                      float* __restrict__ piin)
{
  int idx = blockIdx.x * 256 + threadIdx.x;   // 256*2560
  int b = idx / PIW, c = idx % PIW;
  piin[idx] = (c < OBS) ? taus_t[b * TAU + c] : in[(size_t)b * INW + 1088 + (c - OBS)];
}

// pi input concat final: [obs (inputs cols 0..511), nm_flat broadcast (2048)]
__global__ __launch_bounds__(256)
void k_concat_pi_final(const float* __restrict__ in, const float* __restrict__ nm,
                       float* __restrict__ piin)
{
  int idx = blockIdx.x * 256 + threadIdx.x;
  int b = idx / PIW, c = idx % PIW;
  piin[idx] = (c < OBS) ? in[(size_t)b * INW + c] : nm[c - OBS];
}

__global__ __launch_bounds__(256)
void k_init_h(const float* __restrict__ hid, float* __restrict__ hfa,
              float* __restrict__ hfo, float* __restrict__ hpi)
{
  int idx = blockIdx.x * 256 + threadIdx.x;   // 256*3072
  int b = idx / 3072, c = idx % 3072;
  float v = hid[idx];
  if (c < 1024) hfa[b * 1024 + c] = v;
  else if (c < 2048) hfo[b * 1024 + (c - 1024)] = v;
  else hpi[b * 1024 + (c - 2048)] = v;
}

__global__ __launch_bounds__(256)
void k_init_taus0(const float* __restrict__ in, float* __restrict__ taus)
{
  int idx = blockIdx.x * 256 + threadIdx.x;   // 256*576
  int b = idx / TAU, c = idx % TAU;
  taus[idx] = (c < OBS) ? in[(size_t)b * INW + OBS + c]
                        : in[(size_t)b * INW + 2 * OBS + (c - OBS)];
}

__global__ __launch_bounds__(256)
void k_fill_bias(float* __restrict__ C, const float* __restrict__ bias)
{
  int idx = blockIdx.x * 256 + threadIdx.x;   // 256*1024
  C[idx] = bias[idx & 1023];
}

__global__ __launch_bounds__(256)
void k_relu(float* __restrict__ p)
{
  int idx = blockIdx.x * 256 + threadIdx.x;
  p[idx] = fmaxf(p[idx], 0.f);
}

// vv[t,b,v] = dot(taus[t,b,:], am_vs_w[v,:]) + b[v]
__global__ __launch_bounds__(64)
void k_vv(const float* __restrict__ taus, const float* __restrict__ w,
          const float* __restrict__ bias, float* __restrict__ vv)
{
  int row = blockIdx.x;        // 0..767
  int lane = threadIdx.x;      // 64
  const float* tr = taus + (size_t)row * TAU;
  for (int v = 0; v < 8; ++v) {
    float s = 0.f;
    for (int k = lane; k < TAU; k += 64) s += tr[k] * w[v * TAU + k];
#pragma unroll
    for (int d = 32; d; d >>= 1) s += __shfl_xor(s, d);
    if (lane == 0) vv[row * 8 + v] = s + bias[v];
  }
}

// attention: scores[b,t] = dot(qv[b],kk[t,b])/32; alpha=softmax_t; nm[b]=sum alpha*vv
__global__ __launch_bounds__(64)
void k_attn(const float* __restrict__ qv, const float* __restrict__ kk,
            const float* __restrict__ vv, float* __restrict__ nm,
            float* __restrict__ out_q)
{
  int b = blockIdx.x;          // 256
  int lane = threadIdx.x;      // 64
  const float* qb = qv + (size_t)b * 1024;
  float s[3];
#pragma unroll
  for (int t = 0; t < 3; ++t) {
    const float* kb = kk + (size_t)(t * 256 + b) * 1024;
    float acc = 0.f;
    for (int h = lane; h < 1024; h += 64) acc += qb[h] * kb[h];
#pragma unroll
    for (int d = 32; d; d >>= 1) acc += __shfl_xor(acc, d);
    s[t] = acc * (1.f / 32.f);        // /sqrt(1024)
  }
  float m = fmaxf(s[0], fmaxf(s[1], s[2]));
  float e0 = expf(s[0] - m), e1 = expf(s[1] - m), e2 = expf(s[2] - m);
  float inv = 1.f / (e0 + e1 + e2);
  float a0 = e0 * inv, a1 = e1 * inv, a2 = e2 * inv;
  if (lane < 8) {
    float v = a0 * vv[(0 * 256 + b) * 8 + lane]
            + a1 * vv[(1 * 256 + b) * 8 + lane]
            + a2 * vv[(2 * 256 + b) * 8 + lane];
    nm[b * 8 + lane] = v;
    out_q[b * 72 + lane] = v;
  }
}

__global__ __launch_bounds__(256)
void k_copy_hout(const float* __restrict__ hfa, const float* __restrict__ hfo,
                 float* __restrict__ hout)
{
  int idx = blockIdx.x * 256 + threadIdx.x;   // 256*2048
  int b = idx / 2048, c = idx % 2048;
  float v = (c < 1024) ? hfa[b * 1024 + c] : hfo[b * 1024 + (c - 1024)];
  hout[(size_t)b * 3072 + c] = v;
}

extern "C" void kernel_launch(void* const* d_in, const int* in_sizes, int n_in,
                              void* d_out_v, int out_size, void* d_ws, size_t ws_size,
                              hipStream_t stream)
{
  const float* inputs   = (const float*)d_in[0];
  const float* hidden   = (const float*)d_in[1];
  const float* pi_fc1_w = (const float*)d_in[2];
  const float* pi_fc1_b = (const float*)d_in[3];
  const float* pi_fc2_w = (const float*)d_in[4];
  const float* pi_fc2_b = (const float*)d_in[5];
  const float* fa_fc1_w = (const float*)d_in[6];
  const float* fa_fc1_b = (const float*)d_in[7];
  const float* fa_fc2_w = (const float*)d_in[8];
  const float* fa_fc2_b = (const float*)d_in[9];
  const float* fo_fc1_w = (const float*)d_in[10];
  const float* fo_fc1_b = (const float*)d_in[11];
  const float* fo_fc2_w = (const float*)d_in[12];
  const float* fo_fc2_b = (const float*)d_in[13];
  const float* am_qs_w  = (const float*)d_in[14];
  const float* am_qs_b  = (const float*)d_in[15];
  const float* am_ks_w  = (const float*)d_in[16];
  const float* am_ks_b  = (const float*)d_in[17];
  const float* am_vs_w  = (const float*)d_in[18];
  const float* am_vs_b  = (const float*)d_in[19];
  const float* pi_wih   = (const float*)d_in[20];
  const float* pi_bih   = (const float*)d_in[21];
  const float* pi_whh   = (const float*)d_in[22];
  const float* pi_bhh   = (const float*)d_in[23];
  const float* fa_wih   = (const float*)d_in[24];
  const float* fa_bih   = (const float*)d_in[25];
  const float* fa_whh   = (const float*)d_in[26];
  const float* fa_bhh   = (const float*)d_in[27];
  const float* fo_wih   = (const float*)d_in[28];
  const float* fo_bih   = (const float*)d_in[29];
  const float* fo_whh   = (const float*)d_in[30];
  const float* fo_bhh   = (const float*)d_in[31];

  float* out = (float*)d_out_v;
  float* w = (float*)d_ws;
  // workspace carve (floats)
  float* HFA  = w; w += 256 * 1024;
  float* HFO  = w; w += 256 * 1024;
  float* HPI  = w; w += 256 * 1024;
  float* XBUF = w; w += 256 * 1024;
  float* GI   = w; w += 256 * 3072;
  float* GH   = w; w += 256 * 3072;
  float* QBUF = w; w += (size_t)256 * QN;
  float* X2   = w; w += (size_t)256 * X2W;
  float* TAUS = w; w += 3 * 256 * TAU;
  float* PIIN = w; w += 256 * PIW;
  float* QV   = w; w += 256 * 1024;
  float* KK   = w; w += 768 * 1024;
  float* VV   = w; w += 768 * 8;
  float* NM   = w; w += 2048;

  auto mm = [&](const float* X, int ldx, const float* W, int ldw, const float* bias,
                float* C, int ldc, int M, int N, int K, int act) {
    dim3 g(N / 64, M / 64, 1);
    if (act == 1)
      k_matmul<1, false><<<g, 256, 0, stream>>>(X, ldx, W, ldw, bias, C, ldc, M, N, K, K);
    else
      k_matmul<0, false><<<g, 256, 0, stream>>>(X, ldx, W, ldw, bias, C, ldc, M, N, K, K);
  };
  auto mm_split = [&](const float* X, int ldx, const float* W, int ldw,
                      float* C, int ldc, int M, int N, int K, int splits) {
    int kchunk = ((K / splits + 15) / 16) * 16;
    dim3 g(N / 64, M / 64, splits);
    k_matmul<0, true><<<g, 256, 0, stream>>>(X, ldx, W, ldw, nullptr, C, ldc, M, N, K, kchunk);
  };
  auto gru = [&](const float* x, const float* wih, const float* bih,
                 const float* whh, const float* bhh,
                 const float* hsrc, int ldhs, float* hdst, int ldhd) {
    mm(x, 1024, wih, 1024, bih, GI, 3072, 256, 3072, 1024, 0);
    mm(hsrc, ldhs, whh, 1024, bhh, GH, 3072, 256, 3072, 1024, 0);
    k_gru<<<1024, 256, 0, stream>>>(GI, GH, hsrc, ldhs, hdst, ldhd);
  };

  // init hidden splits + taus[0]
  k_init_h<<<3072, 256, 0, stream>>>(hidden, HFA, HFO, HPI);
  k_init_taus0<<<576, 256, 0, stream>>>(inputs, TAUS);

  for (int t = 0; t < 2; ++t) {
    const float* taus_t = TAUS + (size_t)t * 256 * TAU;
    float* taus_n = TAUS + (size_t)(t + 1) * 256 * TAU;
    // fa branch
    mm(taus_t, TAU, fa_fc1_w, OBS, fa_fc1_b, XBUF, 1024, 256, 1024, OBS, 1);
    gru(XBUF, fa_wih, fa_bih, fa_whh, fa_bhh, HFA, 1024, HFA, 1024);
    mm(HFA, 1024, fa_fc2_w, 1024, fa_fc2_b, QBUF, QN, 256, QN, 1024, 0);
    // build x2 = [scrambled softmax, a, o]
    k_x2_tail<<<576, 256, 0, stream>>>(taus_t, X2);
    k_softmax_scatter<<<16320, 256, 0, stream>>>(QBUF, X2);
    // fo branch (split-K matmul, K=16896)
    k_fill_bias<<<1024, 256, 0, stream>>>(XBUF, fo_fc1_b);
    mm_split(X2, X2W, fo_fc1_w, X2W, XBUF, 1024, 256, 1024, X2W, 4);
    k_relu<<<1024, 256, 0, stream>>>(XBUF);
    gru(XBUF, fo_wih, fo_bih, fo_whh, fo_bhh, HFO, 1024, HFO, 1024);
    mm(HFO, 1024, fo_fc2_w, 1024, fo_fc2_b, taus_n, TAU, 256, OBS, 1024, 0);
    // pi branch (uses o_t, prev_msg, rolling HPI)
    k_concat_pi_loop<<<2560, 256, 0, stream>>>(taus_t, inputs, PIIN);
    mm(PIIN, PIW, pi_fc1_w, PIW, pi_fc1_b, XBUF, 1024, 256, 1024, PIW, 1);
    gru(XBUF, pi_wih, pi_bih, pi_whh, pi_bhh, HPI, 1024, HPI, 1024);
    mm(HPI, 1024, pi_fc2_w, 1024, pi_fc2_b, taus_n + OBS, TAU, 256, 64, 1024, 0);
  }

  // attention
  mm(inputs + 1088, INW, am_qs_w, MSG, am_qs_b, QV, 1024, 256, 1024, MSG, 0);
  mm(TAUS, TAU, am_ks_w, TAU, am_ks_b, KK, 1024, 768, 1024, TAU, 0);
  k_vv<<<768, 64, 0, stream>>>(TAUS, am_vs_w, am_vs_b, VV);
  k_attn<<<256, 64, 0, stream>>>(QV, KK, VV, NM, out);

  // final pi with h_pi0 (NOT rolled HPI)
  k_concat_pi_final<<<2560, 256, 0, stream>>>(inputs, NM, PIIN);
  mm(PIIN, PIW, pi_fc1_w, PIW, pi_fc1_b, XBUF, 1024, 256, 1024, PIW, 1);
  mm(XBUF, 1024, pi_wih, 1024, pi_bih, GI, 3072, 256, 3072, 1024, 0);
  mm(hidden + 2048, 3072, pi_whh, 1024, pi_bhh, GH, 3072, 256, 3072, 1024, 0);
  k_gru<<<1024, 256, 0, stream>>>(GI, GH, hidden + 2048, 3072,
                                  out + 256 * 72 + 2048, 3072);
  mm(out + 256 * 72 + 2048, 3072, pi_fc2_w, 1024, pi_fc2_b, out + 8, 72, 256, 64, 1024, 0);
  k_copy_hout<<<2048, 256, 0, stream>>>(HFA, HFO, out + 256 * 72);
  (void)in_sizes; (void)n_in; (void)out_size; (void)ws_size;
}

// Round 2
// 1194.388 us; speedup vs baseline: 2.2186x; 2.2186x over previous
//
#include <hip/hip_runtime.h>
#include <hip/hip_bf16.h>
#include <math.h>

#define OBS 512
#define MSG 2048
#define TAU 576
#define QN 16320
#define X2W 16896
#define INW 3136
#define PIW 2560

typedef short short8v __attribute__((ext_vector_type(8)));
typedef float f32x4 __attribute__((ext_vector_type(4)));

__device__ inline unsigned bfbits(float x) {
  __hip_bfloat16 h = __float2bfloat16(x);
  return (unsigned)*reinterpret_cast<unsigned short*>(&h);
}

__device__ inline void gload16(const void* g, void* l) {
  __builtin_amdgcn_global_load_lds((__attribute__((address_space(1))) void*)(g),
                                   (__attribute__((address_space(3))) void*)(l), 16, 0, 0);
}

// ---------------- bf16 MFMA NT matmul ----------------
// C[m,n] = act(sum_k A[m,k]*W[n,k] + bias[n]); A: M x K (lda), W: Npad x K (ldw), both bf16.
// BM=BN=128, BK=32, 4 waves. Store guard n < Nlim. ATOMIC: fp32 atomicAdd into C (no bias/act).
template<int ACT, bool ATOMIC>
__global__ __launch_bounds__(256)
void k_mfma(const __hip_bfloat16* __restrict__ A, int lda,
            const __hip_bfloat16* __restrict__ Wt, int ldw,
            const float* __restrict__ bias,
            float* __restrict__ C, int ldc,
            __hip_bfloat16* __restrict__ Cb, int ldcb,
            int Nlim, int kchunk)
{
  __shared__ __hip_bfloat16 As[128 * 32];
  __shared__ __hip_bfloat16 Bs[128 * 32];
  const int tid = threadIdx.x;
  const int wid = tid >> 6, lane = tid & 63;
  const int m0 = blockIdx.y * 128, n0 = blockIdx.x * 128;
  const int k0 = blockIdx.z * kchunk;
  const int wr = wid >> 1, wc = wid & 1;
  f32x4 acc[4][4] = {};

  // staging: wave wid stages rows [wid*32, wid*32+32) of both tiles, 2 x 1KB each
  const int srow = lane >> 2;
  const int scol = (lane & 3) * 8;
  const __hip_bfloat16* ga0 = A + (size_t)(m0 + wid * 32 + srow) * lda + scol;
  const __hip_bfloat16* ga1 = ga0 + (size_t)16 * lda;
  const __hip_bfloat16* gb0 = Wt + (size_t)(n0 + wid * 32 + srow) * ldw + scol;
  const __hip_bfloat16* gb1 = gb0 + (size_t)16 * ldw;
  __hip_bfloat16* la0 = &As[(wid * 32) * 32];
  __hip_bfloat16* la1 = la0 + 16 * 32;
  __hip_bfloat16* lb0 = &Bs[(wid * 32) * 32];
  __hip_bfloat16* lb1 = lb0 + 16 * 32;

  const int fr = lane & 15;          // fragment row / store col
  const int kq = (lane >> 4) * 8;    // fragment k offset
  const int fq = lane >> 4;          // store row quadrant

  const int kend = k0 + kchunk;
  for (int kt = k0; kt < kend; kt += 32) {
    gload16(ga0 + kt, la0);
    gload16(ga1 + kt, la1);
    gload16(gb0 + kt, lb0);
    gload16(gb1 + kt, lb1);
    __syncthreads();
    short8v af[4], bfv[4];
#pragma unroll
    for (int i = 0; i < 4; ++i)
      af[i] = *(const short8v*)&As[(wr * 64 + i * 16 + fr) * 32 + kq];
#pragma unroll
    for (int j = 0; j < 4; ++j)
      bfv[j] = *(const short8v*)&Bs[(wc * 64 + j * 16 + fr) * 32 + kq];
#pragma unroll
    for (int i = 0; i < 4; ++i)
#pragma unroll
      for (int j = 0; j < 4; ++j)
        acc[i][j] = __builtin_amdgcn_mfma_f32_16x16x32_bf16(af[i], bfv[j], acc[i][j], 0, 0, 0);
    __syncthreads();
  }

#pragma unroll
  for (int i = 0; i < 4; ++i) {
    const int mbase = m0 + wr * 64 + i * 16 + fq * 4;
#pragma unroll
    for (int j = 0; j < 4; ++j) {
      const int n = n0 + wc * 64 + j * 16 + fr;
      if (n >= Nlim) continue;
      if (ATOMIC) {
#pragma unroll
        for (int v = 0; v < 4; ++v)
          atomicAdd(&C[(size_t)(mbase + v) * ldc + n], acc[i][j][v]);
      } else {
        const float bb = bias[n];
#pragma unroll
        for (int v = 0; v < 4; ++v) {
          float val = acc[i][j][v] + bb;
          if (ACT) val = fmaxf(val, 0.f);
          if (C)  C[(size_t)(mbase + v) * ldc + n] = val;
          if (Cb) Cb[(size_t)(mbase + v) * ldcb + n] = __float2bfloat16(val);
        }
      }
    }
  }
}

// ---------------- fp32 -> bf16 convert with row padding ----------------
__global__ __launch_bounds__(256)
void k_cvtw(const float* __restrict__ src, int lds_, __hip_bfloat16* __restrict__ dst,
            int N, int K, int Npad)
{
  size_t idx = ((size_t)blockIdx.x * 256 + threadIdx.x) * 8;
  if (idx >= (size_t)Npad * K) return;
  int n = (int)(idx / K);
  int k = (int)(idx % K);
  uint4 o;
  if (n < N) {
    const float* s = src + (size_t)n * lds_ + k;
    float4 v0 = *(const float4*)s;
    float4 v1 = *(const float4*)(s + 4);
    o.x = bfbits(v0.x) | (bfbits(v0.y) << 16);
    o.y = bfbits(v0.z) | (bfbits(v0.w) << 16);
    o.z = bfbits(v1.x) | (bfbits(v1.y) << 16);
    o.w = bfbits(v1.z) | (bfbits(v1.w) << 16);
  } else {
    o = make_uint4(0, 0, 0, 0);
  }
  *(uint4*)(dst + idx) = o;
}

// ---------------- GRU elementwise (fp32 math, dual fp32+bf16 out) ----------------
__global__ __launch_bounds__(256)
void k_gru(const float* __restrict__ gi, const float* __restrict__ gh,
           const float* __restrict__ hs, int ldsrc,
           float* __restrict__ hd, int lddst, __hip_bfloat16* __restrict__ hb)
{
  int idx = blockIdx.x * 256 + threadIdx.x;     // 256*1024
  int b = idx >> 10, j = idx & 1023;
  float ir = gi[b * 3072 + j];
  float iz = gi[b * 3072 + 1024 + j];
  float in_ = gi[b * 3072 + 2048 + j];
  float hr = gh[b * 3072 + j];
  float hz = gh[b * 3072 + 1024 + j];
  float hn = gh[b * 3072 + 2048 + j];
  float r = 1.f / (1.f + expf(-(ir + hr)));
  float z = 1.f / (1.f + expf(-(iz + hz)));
  float n = tanhf(in_ + r * hn);
  float h = hs[(size_t)b * ldsrc + j];
  float o = (1.f - z) * n + z * h;
  hd[(size_t)b * lddst + j] = o;
  hb[idx] = __float2bfloat16(o);
}

// softmax over 64-wide groups of q (bf16, stride 16384), scatter (bf16) into x2
__global__ __launch_bounds__(256)
void k_softmax_scatter(const __hip_bfloat16* __restrict__ q, __hip_bfloat16* __restrict__ x2)
{
  int wid = blockIdx.x * 4 + (threadIdx.x >> 6);
  int lane = threadIdx.x & 63;
  int b = wid / 255, p = wid % 255;
  float v = __bfloat162float(q[(size_t)b * 16384 + p * 64 + lane]);
  float m = v;
#pragma unroll
  for (int s = 32; s; s >>= 1) m = fmaxf(m, __shfl_xor(m, s));
  float e = expf(v - m);
  float sum = e;
#pragma unroll
  for (int s = 32; s; s >>= 1) sum += __shfl_xor(sum, s);
  float r = e / sum;
  int flat = p * 16384 + b * 64 + lane;
  int bp = flat / QN;
  int j = flat - bp * QN;
  x2[(size_t)bp * X2W + j] = __float2bfloat16(r);
}

__global__ __launch_bounds__(256)
void k_x2_tail(const __hip_bfloat16* __restrict__ taus_t, __hip_bfloat16* __restrict__ x2)
{
  int idx = blockIdx.x * 256 + threadIdx.x;   // 256*576
  int b = idx / TAU, c = idx % TAU;
  if (c < 64)
    x2[(size_t)b * X2W + QN + c] = taus_t[b * TAU + OBS + c];
  else
    x2[(size_t)b * X2W + QN + 64 + (c - 64)] = taus_t[b * TAU + (c - 64)];
}

__global__ __launch_bounds__(256)
void k_concat_pi_loop(const __hip_bfloat16* __restrict__ taus_t,
                      const __hip_bfloat16* __restrict__ msg,
                      __hip_bfloat16* __restrict__ piin)
{
  int idx = blockIdx.x * 256 + threadIdx.x;   // 256*2560
  int b = idx / PIW, c = idx % PIW;
  piin[idx] = (c < OBS) ? taus_t[b * TAU + c] : msg[b * MSG + (c - OBS)];
}

__global__ __launch_bounds__(256)
void k_concat_pi_final(const float* __restrict__ in, const float* __restrict__ nm,
                       __hip_bfloat16* __restrict__ piin)
{
  int idx = blockIdx.x * 256 + threadIdx.x;
  int b = idx / PIW, c = idx % PIW;
  float v = (c < OBS) ? in[(size_t)b * INW + c] : nm[c - OBS];
  piin[idx] = __float2bfloat16(v);
}

__global__ __launch_bounds__(256)
void k_init_h(const float* __restrict__ hid,
              float* __restrict__ h32a, float* __restrict__ h32o, float* __restrict__ h32p,
              __hip_bfloat16* __restrict__ hba, __hip_bfloat16* __restrict__ hbo,
              __hip_bfloat16* __restrict__ hbp, __hip_bfloat16* __restrict__ hbp0)
{
  int idx = blockIdx.x * 256 + threadIdx.x;   // 256*3072
  int b = idx / 3072, c = idx % 3072;
  float v = hid[idx];
  __hip_bfloat16 hb = __float2bfloat16(v);
  int j = c & 1023;
  if (c < 1024)      { h32a[b * 1024 + j] = v; hba[b * 1024 + j] = hb; }
  else if (c < 2048) { h32o[b * 1024 + j] = v; hbo[b * 1024 + j] = hb; }
  else               { h32p[b * 1024 + j] = v; hbp[b * 1024 + j] = hb; hbp0[b * 1024 + j] = hb; }
}

__global__ __launch_bounds__(256)
void k_init_taus0(const float* __restrict__ in, __hip_bfloat16* __restrict__ taus)
{
  int idx = blockIdx.x * 256 + threadIdx.x;   // 256*576
  int b = idx / TAU, c = idx % TAU;
  float v = (c < OBS) ? in[(size_t)b * INW + OBS + c]
                      : in[(size_t)b * INW + 2 * OBS + (c - OBS)];
  taus[idx] = __float2bfloat16(v);
}

__global__ __launch_bounds__(256)
void k_fill_bias(float* __restrict__ C, const float* __restrict__ bias)
{
  int idx = blockIdx.x * 256 + threadIdx.x;   // 256*1024
  C[idx] = bias[idx & 1023];
}

__global__ __launch_bounds__(256)
void k_relu_cvt(const float* __restrict__ s, __hip_bfloat16* __restrict__ d)
{
  int idx = blockIdx.x * 256 + threadIdx.x;
  d[idx] = __float2bfloat16(fmaxf(s[idx], 0.f));
}

__global__ __launch_bounds__(64)
void k_vv(const __hip_bfloat16* __restrict__ taus, const float* __restrict__ w,
          const float* __restrict__ bias, float* __restrict__ vv)
{
  int row = blockIdx.x;        // 0..767
  int lane = threadIdx.x;
  const __hip_bfloat16* tr = taus + (size_t)row * TAU;
  for (int v = 0; v < 8; ++v) {
    float s = 0.f;
    for (int k = lane; k < TAU; k += 64) s += __bfloat162float(tr[k]) * w[v * TAU + k];
#pragma unroll
    for (int d = 32; d; d >>= 1) s += __shfl_xor(s, d);
    if (lane == 0) vv[row * 8 + v] = s + bias[v];
  }
}

__global__ __launch_bounds__(64)
void k_attn(const float* __restrict__ qv, const float* __restrict__ kk,
            const float* __restrict__ vv, float* __restrict__ nm,
            float* __restrict__ out_q)
{
  int b = blockIdx.x;
  int lane = threadIdx.x;
  const float* qb = qv + (size_t)b * 1024;
  float s[3];
#pragma unroll
  for (int t = 0; t < 3; ++t) {
    const float* kb = kk + (size_t)(t * 256 + b) * 1024;
    float acc = 0.f;
    for (int h = lane; h < 1024; h += 64) acc += qb[h] * kb[h];
#pragma unroll
    for (int d = 32; d; d >>= 1) acc += __shfl_xor(acc, d);
    s[t] = acc * (1.f / 32.f);
  }
  float m = fmaxf(s[0], fmaxf(s[1], s[2]));
  float e0 = expf(s[0] - m), e1 = expf(s[1] - m), e2 = expf(s[2] - m);
  float inv = 1.f / (e0 + e1 + e2);
  float a0 = e0 * inv, a1 = e1 * inv, a2 = e2 * inv;
  if (lane < 8) {
    float v = a0 * vv[(0 * 256 + b) * 8 + lane]
            + a1 * vv[(1 * 256 + b) * 8 + lane]
            + a2 * vv[(2 * 256 + b) * 8 + lane];
    nm[b * 8 + lane] = v;
    out_q[b * 72 + lane] = v;
  }
}

__global__ __launch_bounds__(256)
void k_copy_hout(const float* __restrict__ hfa, const float* __restrict__ hfo,
                 float* __restrict__ hout)
{
  int idx = blockIdx.x * 256 + threadIdx.x;   // 256*2048
  int b = idx / 2048, c = idx % 2048;
  float v = (c < 1024) ? hfa[b * 1024 + c] : hfo[b * 1024 + (c - 1024)];
  hout[(size_t)b * 3072 + c] = v;
}

extern "C" void kernel_launch(void* const* d_in, const int* in_sizes, int n_in,
                              void* d_out_v, int out_size, void* d_ws, size_t ws_size,
                              hipStream_t stream)
{
  const float* inputs   = (const float*)d_in[0];
  const float* hidden   = (const float*)d_in[1];
  const float* pi_fc1_w = (const float*)d_in[2];
  const float* pi_fc1_b = (const float*)d_in[3];
  const float* pi_fc2_w = (const float*)d_in[4];
  const float* pi_fc2_b = (const float*)d_in[5];
  const float* fa_fc1_w = (const float*)d_in[6];
  const float* fa_fc1_b = (const float*)d_in[7];
  const float* fa_fc2_w = (const float*)d_in[8];
  const float* fa_fc2_b = (const float*)d_in[9];
  const float* fo_fc1_w = (const float*)d_in[10];
  const float* fo_fc1_b = (const float*)d_in[11];
  const float* fo_fc2_w = (const float*)d_in[12];
  const float* fo_fc2_b = (const float*)d_in[13];
  const float* am_qs_w  = (const float*)d_in[14];
  const float* am_qs_b  = (const float*)d_in[15];
  const float* am_ks_w  = (const float*)d_in[16];
  const float* am_ks_b  = (const float*)d_in[17];
  const float* am_vs_w  = (const float*)d_in[18];
  const float* am_vs_b  = (const float*)d_in[19];
  const float* pi_wih   = (const float*)d_in[20];
  const float* pi_bih   = (const float*)d_in[21];
  const float* pi_whh   = (const float*)d_in[22];
  const float* pi_bhh   = (const float*)d_in[23];
  const float* fa_wih   = (const float*)d_in[24];
  const float* fa_bih   = (const float*)d_in[25];
  const float* fa_whh   = (const float*)d_in[26];
  const float* fa_bhh   = (const float*)d_in[27];
  const float* fo_wih   = (const float*)d_in[28];
  const float* fo_bih   = (const float*)d_in[29];
  const float* fo_whh   = (const float*)d_in[30];
  const float* fo_bhh   = (const float*)d_in[31];

  float* out = (float*)d_out_v;
  char* p = (char*)d_ws;
  auto alloc = [&](size_t bytes) { void* r = p; p += (bytes + 255) & ~(size_t)255; return r; };
  typedef __hip_bfloat16 bf;

  // bf16 weights
  bf* WPI1 = (bf*)alloc((size_t)1024 * 2560 * 2);
  bf* WPI2 = (bf*)alloc((size_t)128 * 1024 * 2);
  bf* WFA1 = (bf*)alloc((size_t)1024 * 512 * 2);
  bf* WFA2 = (bf*)alloc((size_t)16384 * 1024 * 2);
  bf* WFO1 = (bf*)alloc((size_t)1024 * 16896 * 2);
  bf* WFO2 = (bf*)alloc((size_t)512 * 1024 * 2);
  bf* WQS  = (bf*)alloc((size_t)1024 * 2048 * 2);
  bf* WKS  = (bf*)alloc((size_t)1024 * 576 * 2);
  bf* WPIIH = (bf*)alloc((size_t)3072 * 1024 * 2);
  bf* WPIHH = (bf*)alloc((size_t)3072 * 1024 * 2);
  bf* WFAIH = (bf*)alloc((size_t)3072 * 1024 * 2);
  bf* WFAHH = (bf*)alloc((size_t)3072 * 1024 * 2);
  bf* WFOIH = (bf*)alloc((size_t)3072 * 1024 * 2);
  bf* WFOHH = (bf*)alloc((size_t)3072 * 1024 * 2);
  // bf16 activations
  bf* HFAB = (bf*)alloc((size_t)256 * 1024 * 2);
  bf* HFOB = (bf*)alloc((size_t)256 * 1024 * 2);
  bf* HPIB = (bf*)alloc((size_t)256 * 1024 * 2);
  bf* HPI0B = (bf*)alloc((size_t)256 * 1024 * 2);
  bf* XBUFB = (bf*)alloc((size_t)256 * 1024 * 2);
  bf* TAUSB = (bf*)alloc((size_t)3 * 256 * TAU * 2);
  bf* X2B  = (bf*)alloc((size_t)256 * X2W * 2);
  bf* PIINB = (bf*)alloc((size_t)256 * PIW * 2);
  bf* MSGB = (bf*)alloc((size_t)256 * MSG * 2);
  bf* QBUFB = (bf*)alloc((size_t)256 * 16384 * 2);
  // fp32
  float* HFA32 = (float*)alloc((size_t)256 * 1024 * 4);
  float* HFO32 = (float*)alloc((size_t)256 * 1024 * 4);
  float* HPI32 = (float*)alloc((size_t)256 * 1024 * 4);
  float* XBUF32 = (float*)alloc((size_t)256 * 1024 * 4);
  float* GI = (float*)alloc((size_t)256 * 3072 * 4);
  float* GH = (float*)alloc((size_t)256 * 3072 * 4);
  float* QV = (float*)alloc((size_t)256 * 1024 * 4);
  float* KK = (float*)alloc((size_t)768 * 1024 * 4);
  float* VV = (float*)alloc((size_t)768 * 8 * 4);
  float* NM = (float*)alloc((size_t)2048 * 4);

  auto cvt = [&](const float* src, int lds_, bf* dst, int N, int K, int Npad) {
    size_t total = ((size_t)Npad * K) / 8;
    int blocks = (int)((total + 255) / 256);
    k_cvtw<<<blocks, 256, 0, stream>>>(src, lds_, dst, N, K, Npad);
  };
  auto mm = [&](const bf* Aa, int lda, const bf* Ww, int ldw, const float* bias,
                float* C, int ldc, bf* Cb, int ldcb,
                int M, int Npad, int Nlim, int K, int act) {
    dim3 g(Npad / 128, M / 128, 1);
    if (act) k_mfma<1, false><<<g, 256, 0, stream>>>(Aa, lda, Ww, ldw, bias, C, ldc, Cb, ldcb, Nlim, K);
    else     k_mfma<0, false><<<g, 256, 0, stream>>>(Aa, lda, Ww, ldw, bias, C, ldc, Cb, ldcb, Nlim, K);
  };

  // weight + input conversions
  cvt(pi_fc1_w, 2560, WPI1, 1024, 2560, 1024);
  cvt(pi_fc2_w, 1024, WPI2, 64, 1024, 128);
  cvt(fa_fc1_w, 512,  WFA1, 1024, 512, 1024);
  cvt(fa_fc2_w, 1024, WFA2, 16320, 1024, 16384);
  cvt(fo_fc1_w, 16896, WFO1, 1024, 16896, 1024);
  cvt(fo_fc2_w, 1024, WFO2, 512, 1024, 512);
  cvt(am_qs_w, 2048, WQS, 1024, 2048, 1024);
  cvt(am_ks_w, 576, WKS, 1024, 576, 1024);
  cvt(pi_wih, 1024, WPIIH, 3072, 1024, 3072);
  cvt(pi_whh, 1024, WPIHH, 3072, 1024, 3072);
  cvt(fa_wih, 1024, WFAIH, 3072, 1024, 3072);
  cvt(fa_whh, 1024, WFAHH, 3072, 1024, 3072);
  cvt(fo_wih, 1024, WFOIH, 3072, 1024, 3072);
  cvt(fo_whh, 1024, WFOHH, 3072, 1024, 3072);
  cvt(inputs + 1088, INW, MSGB, 256, 2048, 256);

  k_init_h<<<3072, 256, 0, stream>>>(hidden, HFA32, HFO32, HPI32, HFAB, HFOB, HPIB, HPI0B);
  k_init_taus0<<<576, 256, 0, stream>>>(inputs, TAUSB);

  for (int t = 0; t < 2; ++t) {
    bf* taus_t = TAUSB + (size_t)t * 256 * TAU;
    bf* taus_n = TAUSB + (size_t)(t + 1) * 256 * TAU;
    // fa branch
    mm(taus_t, TAU, WFA1, 512, fa_fc1_b, nullptr, 0, XBUFB, 1024, 256, 1024, 1024, 512, 1);
    mm(XBUFB, 1024, WFAIH, 1024, fa_bih, GI, 3072, nullptr, 0, 256, 3072, 3072, 1024, 0);
    mm(HFAB, 1024, WFAHH, 1024, fa_bhh, GH, 3072, nullptr, 0, 256, 3072, 3072, 1024, 0);
    k_gru<<<1024, 256, 0, stream>>>(GI, GH, HFA32, 1024, HFA32, 1024, HFAB);
    mm(HFAB, 1024, WFA2, 1024, fa_fc2_b, nullptr, 0, QBUFB, 16384, 256, 16384, 16320, 1024, 0);
    // x2 = [scrambled softmax | a | o]
    k_x2_tail<<<576, 256, 0, stream>>>(taus_t, X2B);
    k_softmax_scatter<<<16320, 256, 0, stream>>>(QBUFB, X2B);
    // fo branch (split-K 16, atomic fp32)
    k_fill_bias<<<1024, 256, 0, stream>>>(XBUF32, fo_fc1_b);
    {
      dim3 g(1024 / 128, 256 / 128, 16);
      k_mfma<0, true><<<g, 256, 0, stream>>>(X2B, X2W, WFO1, X2W, nullptr,
                                             XBUF32, 1024, nullptr, 0, 1024, 1056);
    }
    k_relu_cvt<<<1024, 256, 0, stream>>>(XBUF32, XBUFB);
    mm(XBUFB, 1024, WFOIH, 1024, fo_bih, GI, 3072, nullptr, 0, 256, 3072, 3072, 1024, 0);
    mm(HFOB, 1024, WFOHH, 1024, fo_bhh, GH, 3072, nullptr, 0, 256, 3072, 3072, 1024, 0);
    k_gru<<<1024, 256, 0, stream>>>(GI, GH, HFO32, 1024, HFO32, 1024, HFOB);
    mm(HFOB, 1024, WFO2, 1024, fo_fc2_b, nullptr, 0, taus_n, TAU, 256, 512, 512, 1024, 0);
    // pi branch
    k_concat_pi_loop<<<2560, 256, 0, stream>>>(taus_t, MSGB, PIINB);
    mm(PIINB, PIW, WPI1, PIW, pi_fc1_b, nullptr, 0, XBUFB, 1024, 256, 1024, 1024, 2560, 1);
    mm(XBUFB, 1024, WPIIH, 1024, pi_bih, GI, 3072, nullptr, 0, 256, 3072, 3072, 1024, 0);
    mm(HPIB, 1024, WPIHH, 1024, pi_bhh, GH, 3072, nullptr, 0, 256, 3072, 3072, 1024, 0);
    k_gru<<<1024, 256, 0, stream>>>(GI, GH, HPI32, 1024, HPI32, 1024, HPIB);
    mm(HPIB, 1024, WPI2, 1024, pi_fc2_b, nullptr, 0, taus_n + OBS, TAU, 256, 128, 64, 1024, 0);
  }

  // attention
  mm(MSGB, MSG, WQS, MSG, am_qs_b, QV, 1024, nullptr, 0, 256, 1024, 1024, 2048, 0);
  mm(TAUSB, TAU, WKS, TAU, am_ks_b, KK, 1024, nullptr, 0, 768, 1024, 1024, 576, 0);
  k_vv<<<768, 64, 0, stream>>>(TAUSB, am_vs_w, am_vs_b, VV);
  k_attn<<<256, 64, 0, stream>>>(QV, KK, VV, NM, out);

  // final pi with original h_pi0
  k_concat_pi_final<<<2560, 256, 0, stream>>>(inputs, NM, PIINB);
  mm(PIINB, PIW, WPI1, PIW, pi_fc1_b, nullptr, 0, XBUFB, 1024, 256, 1024, 1024, 2560, 1);
  mm(XBUFB, 1024, WPIIH, 1024, pi_bih, GI, 3072, nullptr, 0, 256, 3072, 3072, 1024, 0);
  mm(HPI0B, 1024, WPIHH, 1024, pi_bhh, GH, 3072, nullptr, 0, 256, 3072, 3072, 1024, 0);
  k_gru<<<1024, 256, 0, stream>>>(GI, GH, hidden + 2048, 3072,
                                  out + 256 * 72 + 2048, 3072, HPIB);
  mm(HPIB, 1024, WPI2, 1024, pi_fc2_b, out + 8, 72, nullptr, 0, 256, 128, 64, 1024, 0);
  k_copy_hout<<<2048, 256, 0, stream>>>(HFA32, HFO32, out + 256 * 72);
  (void)in_sizes; (void)n_in; (void)out_size; (void)ws_size;
}

// Round 3
// 626.178 us; speedup vs baseline: 4.2318x; 1.9074x over previous
//
#include <hip/hip_runtime.h>
#include <hip/hip_bf16.h>
#include <math.h>

#define OBS 512
#define MSG 2048
#define TAU 576
#define TAUP 640      // padded taus row stride (K multiple of 128)
#define QN 16320
#define X2W 16896
#define INW 3136
#define PIW 2560

typedef short short8v __attribute__((ext_vector_type(8)));
typedef float f32x4 __attribute__((ext_vector_type(4)));

__device__ inline unsigned bfbits(float x) {
  __hip_bfloat16 h = __float2bfloat16(x);
  return (unsigned)*reinterpret_cast<unsigned short*>(&h);
}

__device__ inline void gload16(const void* g, void* l) {
  __builtin_amdgcn_global_load_lds((__attribute__((address_space(1))) void*)(g),
                                   (__attribute__((address_space(3))) void*)(l), 16, 0, 0);
}

// ---------------- bf16 MFMA NT matmul, BM=BN=64, BK=128, double-buffered ----------------
// C[m,n] = act(sum_k A[m,k]*W[n,k] + bias[n]); A: M x K (lda), W: Npad x K (ldw), bf16.
// 4 waves, each 32x32 output. XOR-swizzled LDS (pre-swizzled global source, rule #21).
// ATOMIC: fp32 atomicAdd partials into C (bias/act skipped). k0 = blockIdx.z*nsteps*128.
template<int ACT, bool ATOMIC>
__global__ __launch_bounds__(256)
void k_mfma(const __hip_bfloat16* __restrict__ A, int lda,
            const __hip_bfloat16* __restrict__ Wt, int ldw,
            const float* __restrict__ bias,
            float* __restrict__ C, int ldc,
            __hip_bfloat16* __restrict__ Cb, int ldcb,
            int Nlim, int nsteps)
{
  __shared__ __hip_bfloat16 As[2][64 * 128];
  __shared__ __hip_bfloat16 Bs[2][64 * 128];
  const int tid = threadIdx.x;
  const int lane = tid & 63;
  const int wid = tid >> 6;
  const int m0 = blockIdx.y * 64, n0 = blockIdx.x * 64;
  const int wr = wid >> 1, wc = wid & 1;
  const int fr = lane & 15, q = lane >> 4;
  const size_t k0 = (size_t)blockIdx.z * nsteps * 128;

  const __hip_bfloat16* Ab = A + (size_t)m0 * lda + k0;
  const __hip_bfloat16* Bb = Wt + (size_t)n0 * ldw + k0;

  // staging map: 4 rounds x 256 threads of 16B chunks; 16 chunks per 128-col row.
  // LDS linear; global col-chunk XOR-swizzled by (row&7).
  int srow[4], scol[4], sdst[4];
#pragma unroll
  for (int r = 0; r < 4; ++r) {
    int chunk = r * 256 + tid;
    srow[r] = chunk >> 4;
    int c = chunk & 15;
    scol[r] = (c ^ (srow[r] & 7)) * 8;
    sdst[r] = chunk * 8;
  }

  const int arow0 = wr * 32 + fr, arow1 = arow0 + 16;
  const int brow0 = wc * 32 + fr, brow1 = brow0 + 16;
  const int amask = arow0 & 7, bmask = brow0 & 7;   // (+16 keeps &7)

  f32x4 acc[2][2] = {};

  // prologue
#pragma unroll
  for (int r = 0; r < 4; ++r)
    gload16(Ab + (size_t)srow[r] * lda + scol[r], &As[0][sdst[r]]);
#pragma unroll
  for (int r = 0; r < 4; ++r)
    gload16(Bb + (size_t)srow[r] * ldw + scol[r], &Bs[0][sdst[r]]);
  __syncthreads();

  for (int t = 0; t < nsteps; ++t) {
    if (t + 1 < nsteps) {
      const int kt = (t + 1) * 128;
      const int buf = (t + 1) & 1;
#pragma unroll
      for (int r = 0; r < 4; ++r)
        gload16(Ab + (size_t)srow[r] * lda + kt + scol[r], &As[buf][sdst[r]]);
#pragma unroll
      for (int r = 0; r < 4; ++r)
        gload16(Bb + (size_t)srow[r] * ldw + kt + scol[r], &Bs[buf][sdst[r]]);
    }
    const __hip_bfloat16* Ac = As[t & 1];
    const __hip_bfloat16* Bc = Bs[t & 1];
#pragma unroll
    for (int ks = 0; ks < 4; ++ks) {
      const int cc = ks * 4 + q;
      short8v a0 = *(const short8v*)&Ac[arow0 * 128 + ((cc ^ amask) << 3)];
      short8v a1 = *(const short8v*)&Ac[arow1 * 128 + ((cc ^ amask) << 3)];
      short8v b0 = *(const short8v*)&Bc[brow0 * 128 + ((cc ^ bmask) << 3)];
      short8v b1 = *(const short8v*)&Bc[brow1 * 128 + ((cc ^ bmask) << 3)];
      acc[0][0] = __builtin_amdgcn_mfma_f32_16x16x32_bf16(a0, b0, acc[0][0], 0, 0, 0);
      acc[0][1] = __builtin_amdgcn_mfma_f32_16x16x32_bf16(a0, b1, acc[0][1], 0, 0, 0);
      acc[1][0] = __builtin_amdgcn_mfma_f32_16x16x32_bf16(a1, b0, acc[1][0], 0, 0, 0);
      acc[1][1] = __builtin_amdgcn_mfma_f32_16x16x32_bf16(a1, b1, acc[1][1], 0, 0, 0);
    }
    __syncthreads();   // drains prefetch vmcnt + protects buffer reuse
  }

#pragma unroll
  for (int i = 0; i < 2; ++i) {
    const int mbase = m0 + wr * 32 + i * 16 + q * 4;
#pragma unroll
    for (int j = 0; j < 2; ++j) {
      const int n = n0 + wc * 32 + j * 16 + fr;
      if (n >= Nlim) continue;
      if (ATOMIC) {
#pragma unroll
        for (int v = 0; v < 4; ++v)
          atomicAdd(&C[(size_t)(mbase + v) * ldc + n], acc[i][j][v]);
      } else {
        const float bb = bias[n];
#pragma unroll
        for (int v = 0; v < 4; ++v) {
          float val = acc[i][j][v] + bb;
          if (ACT) val = fmaxf(val, 0.f);
          if (C)  C[(size_t)(mbase + v) * ldc + n] = val;
          if (Cb) Cb[(size_t)(mbase + v) * ldcb + n] = __float2bfloat16(val);
        }
      }
    }
  }
}

// ---------------- fp32 -> bf16 convert, row pad to Npad, col pad Kval->Kdst ----------------
__global__ __launch_bounds__(256)
void k_cvtw(const float* __restrict__ src, int lds_, __hip_bfloat16* __restrict__ dst,
            int N, int Kdst, int Kval, int Npad)
{
  size_t idx = ((size_t)blockIdx.x * 256 + threadIdx.x) * 8;
  if (idx >= (size_t)Npad * Kdst) return;
  int n = (int)(idx / Kdst);
  int k = (int)(idx % Kdst);
  uint4 o;
  if (n < N && k < Kval) {
    const float* s = src + (size_t)n * lds_ + k;
    float4 v0 = *(const float4*)s;
    float4 v1 = *(const float4*)(s + 4);
    o.x = bfbits(v0.x) | (bfbits(v0.y) << 16);
    o.y = bfbits(v0.z) | (bfbits(v0.w) << 16);
    o.z = bfbits(v1.x) | (bfbits(v1.y) << 16);
    o.w = bfbits(v1.z) | (bfbits(v1.w) << 16);
  } else {
    o = make_uint4(0, 0, 0, 0);
  }
  *(uint4*)(dst + idx) = o;
}

// ---------------- GRU elementwise (fp32 math, dual fp32+bf16 out) ----------------
__global__ __launch_bounds__(256)
void k_gru(const float* __restrict__ gi, const float* __restrict__ gh,
           const float* __restrict__ hs, int ldsrc,
           float* __restrict__ hd, int lddst, __hip_bfloat16* __restrict__ hb)
{
  int idx = blockIdx.x * 256 + threadIdx.x;     // 256*1024
  int b = idx >> 10, j = idx & 1023;
  float ir = gi[b * 3072 + j];
  float iz = gi[b * 3072 + 1024 + j];
  float in_ = gi[b * 3072 + 2048 + j];
  float hr = gh[b * 3072 + j];
  float hz = gh[b * 3072 + 1024 + j];
  float hn = gh[b * 3072 + 2048 + j];
  float r = 1.f / (1.f + expf(-(ir + hr)));
  float z = 1.f / (1.f + expf(-(iz + hz)));
  float n = tanhf(in_ + r * hn);
  float h = hs[(size_t)b * ldsrc + j];
  float o = (1.f - z) * n + z * h;
  hd[(size_t)b * lddst + j] = o;
  hb[idx] = __float2bfloat16(o);
}

// softmax over 64-wide groups of q (bf16, stride QN), scatter (bf16) into x2
__global__ __launch_bounds__(256)
void k_softmax_scatter(const __hip_bfloat16* __restrict__ q, __hip_bfloat16* __restrict__ x2)
{
  int wid = blockIdx.x * 4 + (threadIdx.x >> 6);
  int lane = threadIdx.x & 63;
  int b = wid / 255, p = wid % 255;
  float v = __bfloat162float(q[(size_t)b * QN + p * 64 + lane]);
  float m = v;
#pragma unroll
  for (int s = 32; s; s >>= 1) m = fmaxf(m, __shfl_xor(m, s));
  float e = expf(v - m);
  float sum = e;
#pragma unroll
  for (int s = 32; s; s >>= 1) sum += __shfl_xor(sum, s);
  float r = e / sum;
  int flat = p * 16384 + b * 64 + lane;
  int bp = flat / QN;
  int j = flat - bp * QN;
  x2[(size_t)bp * X2W + j] = __float2bfloat16(r);
}

__global__ __launch_bounds__(256)
void k_x2_tail(const __hip_bfloat16* __restrict__ taus_t, __hip_bfloat16* __restrict__ x2)
{
  int idx = blockIdx.x * 256 + threadIdx.x;   // 256*576
  int b = idx / TAU, c = idx % TAU;
  if (c < 64)
    x2[(size_t)b * X2W + QN + c] = taus_t[(size_t)b * TAUP + OBS + c];
  else
    x2[(size_t)b * X2W + QN + 64 + (c - 64)] = taus_t[(size_t)b * TAUP + (c - 64)];
}

__global__ __launch_bounds__(256)
void k_concat_pi_loop(const __hip_bfloat16* __restrict__ taus_t,
                      const __hip_bfloat16* __restrict__ msg,
                      __hip_bfloat16* __restrict__ piin)
{
  int idx = blockIdx.x * 256 + threadIdx.x;   // 256*2560
  int b = idx / PIW, c = idx % PIW;
  piin[idx] = (c < OBS) ? taus_t[(size_t)b * TAUP + c] : msg[b * MSG + (c - OBS)];
}

__global__ __launch_bounds__(256)
void k_concat_pi_final(const float* __restrict__ in, const float* __restrict__ nm,
                       __hip_bfloat16* __restrict__ piin)
{
  int idx = blockIdx.x * 256 + threadIdx.x;
  int b = idx / PIW, c = idx % PIW;
  float v = (c < OBS) ? in[(size_t)b * INW + c] : nm[c - OBS];
  piin[idx] = __float2bfloat16(v);
}

__global__ __launch_bounds__(256)
void k_init_h(const float* __restrict__ hid,
              float* __restrict__ h32a, float* __restrict__ h32o, float* __restrict__ h32p,
              __hip_bfloat16* __restrict__ hba, __hip_bfloat16* __restrict__ hbo,
              __hip_bfloat16* __restrict__ hbp, __hip_bfloat16* __restrict__ hbp0)
{
  int idx = blockIdx.x * 256 + threadIdx.x;   // 256*3072
  int b = idx / 3072, c = idx % 3072;
  float v = hid[idx];
  __hip_bfloat16 hb = __float2bfloat16(v);
  int j = c & 1023;
  if (c < 1024)      { h32a[b * 1024 + j] = v; hba[b * 1024 + j] = hb; }
  else if (c < 2048) { h32o[b * 1024 + j] = v; hbo[b * 1024 + j] = hb; }
  else               { h32p[b * 1024 + j] = v; hbp[b * 1024 + j] = hb; hbp0[b * 1024 + j] = hb; }
}

// init all 3 taus slabs (stride TAUP): t=0 valid cols from inputs, everything else 0
__global__ __launch_bounds__(256)
void k_init_taus(const float* __restrict__ in, __hip_bfloat16* __restrict__ taus)
{
  int idx = blockIdx.x * 256 + threadIdx.x;   // 3*256*TAUP
  int t = idx / (256 * TAUP);
  int r = (idx / TAUP) % 256;
  int c = idx % TAUP;
  float v = 0.f;
  if (t == 0 && c < TAU)
    v = (c < OBS) ? in[(size_t)r * INW + OBS + c]
                  : in[(size_t)r * INW + 2 * OBS + (c - OBS)];
  taus[idx] = __float2bfloat16(v);
}

__global__ __launch_bounds__(256)
void k_fill_bias(float* __restrict__ C, const float* __restrict__ bias)
{
  int idx = blockIdx.x * 256 + threadIdx.x;   // 256*1024
  C[idx] = bias[idx & 1023];
}

__global__ __launch_bounds__(256)
void k_relu_cvt(const float* __restrict__ s, __hip_bfloat16* __restrict__ d)
{
  int idx = blockIdx.x * 256 + threadIdx.x;
  d[idx] = __float2bfloat16(fmaxf(s[idx], 0.f));
}

__global__ __launch_bounds__(64)
void k_vv(const __hip_bfloat16* __restrict__ taus, const float* __restrict__ w,
          const float* __restrict__ bias, float* __restrict__ vv)
{
  int row = blockIdx.x;        // 0..767
  int lane = threadIdx.x;
  const __hip_bfloat16* tr = taus + (size_t)row * TAUP;
  for (int v = 0; v < 8; ++v) {
    float s = 0.f;
    for (int k = lane; k < TAU; k += 64) s += __bfloat162float(tr[k]) * w[v * TAU + k];
#pragma unroll
    for (int d = 32; d; d >>= 1) s += __shfl_xor(s, d);
    if (lane == 0) vv[row * 8 + v] = s + bias[v];
  }
}

__global__ __launch_bounds__(64)
void k_attn(const float* __restrict__ qv, const float* __restrict__ kk,
            const float* __restrict__ vv, float* __restrict__ nm,
            float* __restrict__ out_q)
{
  int b = blockIdx.x;
  int lane = threadIdx.x;
  const float* qb = qv + (size_t)b * 1024;
  float s[3];
#pragma unroll
  for (int t = 0; t < 3; ++t) {
    const float* kb = kk + (size_t)(t * 256 + b) * 1024;
    float acc = 0.f;
    for (int h = lane; h < 1024; h += 64) acc += qb[h] * kb[h];
#pragma unroll
    for (int d = 32; d; d >>= 1) acc += __shfl_xor(acc, d);
    s[t] = acc * (1.f / 32.f);
  }
  float m = fmaxf(s[0], fmaxf(s[1], s[2]));
  float e0 = expf(s[0] - m), e1 = expf(s[1] - m), e2 = expf(s[2] - m);
  float inv = 1.f / (e0 + e1 + e2);
  float a0 = e0 * inv, a1 = e1 * inv, a2 = e2 * inv;
  if (lane < 8) {
    float v = a0 * vv[(0 * 256 + b) * 8 + lane]
            + a1 * vv[(1 * 256 + b) * 8 + lane]
            + a2 * vv[(2 * 256 + b) * 8 + lane];
    nm[b * 8 + lane] = v;
    out_q[b * 72 + lane] = v;
  }
}

__global__ __launch_bounds__(256)
void k_copy_hout(const float* __restrict__ hfa, const float* __restrict__ hfo,
                 float* __restrict__ hout)
{
  int idx = blockIdx.x * 256 + threadIdx.x;   // 256*2048
  int b = idx / 2048, c = idx % 2048;
  float v = (c < 1024) ? hfa[b * 1024 + c] : hfo[b * 1024 + (c - 1024)];
  hout[(size_t)b * 3072 + c] = v;
}

extern "C" void kernel_launch(void* const* d_in, const int* in_sizes, int n_in,
                              void* d_out_v, int out_size, void* d_ws, size_t ws_size,
                              hipStream_t stream)
{
  const float* inputs   = (const float*)d_in[0];
  const float* hidden   = (const float*)d_in[1];
  const float* pi_fc1_w = (const float*)d_in[2];
  const float* pi_fc1_b = (const float*)d_in[3];
  const float* pi_fc2_w = (const float*)d_in[4];
  const float* pi_fc2_b = (const float*)d_in[5];
  const float* fa_fc1_w = (const float*)d_in[6];
  const float* fa_fc1_b = (const float*)d_in[7];
  const float* fa_fc2_w = (const float*)d_in[8];
  const float* fa_fc2_b = (const float*)d_in[9];
  const float* fo_fc1_w = (const float*)d_in[10];
  const float* fo_fc1_b = (const float*)d_in[11];
  const float* fo_fc2_w = (const float*)d_in[12];
  const float* fo_fc2_b = (const float*)d_in[13];
  const float* am_qs_w  = (const float*)d_in[14];
  const float* am_qs_b  = (const float*)d_in[15];
  const float* am_ks_w  = (const float*)d_in[16];
  const float* am_ks_b  = (const float*)d_in[17];
  const float* am_vs_w  = (const float*)d_in[18];
  const float* am_vs_b  = (const float*)d_in[19];
  const float* pi_wih   = (const float*)d_in[20];
  const float* pi_bih   = (const float*)d_in[21];
  const float* pi_whh   = (const float*)d_in[22];
  const float* pi_bhh   = (const float*)d_in[23];
  const float* fa_wih   = (const float*)d_in[24];
  const float* fa_bih   = (const float*)d_in[25];
  const float* fa_whh   = (const float*)d_in[26];
  const float* fa_bhh   = (const float*)d_in[27];
  const float* fo_wih   = (const float*)d_in[28];
  const float* fo_bih   = (const float*)d_in[29];
  const float* fo_whh   = (const float*)d_in[30];
  const float* fo_bhh   = (const float*)d_in[31];

  float* out = (float*)d_out_v;
  char* p = (char*)d_ws;
  auto alloc = [&](size_t bytes) { void* r = p; p += (bytes + 255) & ~(size_t)255; return r; };
  typedef __hip_bfloat16 bf;

  // bf16 weights
  bf* WPI1 = (bf*)alloc((size_t)1024 * 2560 * 2);
  bf* WPI2 = (bf*)alloc((size_t)64 * 1024 * 2);
  bf* WFA1 = (bf*)alloc((size_t)1024 * 512 * 2);
  bf* WFA2 = (bf*)alloc((size_t)16320 * 1024 * 2);
  bf* WFO1 = (bf*)alloc((size_t)1024 * 16896 * 2);
  bf* WFO2 = (bf*)alloc((size_t)512 * 1024 * 2);
  bf* WQS  = (bf*)alloc((size_t)1024 * 2048 * 2);
  bf* WKS  = (bf*)alloc((size_t)1024 * TAUP * 2);
  bf* WPIIH = (bf*)alloc((size_t)3072 * 1024 * 2);
  bf* WPIHH = (bf*)alloc((size_t)3072 * 1024 * 2);
  bf* WFAIH = (bf*)alloc((size_t)3072 * 1024 * 2);
  bf* WFAHH = (bf*)alloc((size_t)3072 * 1024 * 2);
  bf* WFOIH = (bf*)alloc((size_t)3072 * 1024 * 2);
  bf* WFOHH = (bf*)alloc((size_t)3072 * 1024 * 2);
  // bf16 activations
  bf* HFAB = (bf*)alloc((size_t)256 * 1024 * 2);
  bf* HFOB = (bf*)alloc((size_t)256 * 1024 * 2);
  bf* HPIB = (bf*)alloc((size_t)256 * 1024 * 2);
  bf* HPI0B = (bf*)alloc((size_t)256 * 1024 * 2);
  bf* XBUFB = (bf*)alloc((size_t)256 * 1024 * 2);
  bf* TAUSB = (bf*)alloc((size_t)3 * 256 * TAUP * 2);
  bf* X2B  = (bf*)alloc((size_t)256 * X2W * 2);
  bf* PIINB = (bf*)alloc((size_t)256 * PIW * 2);
  bf* MSGB = (bf*)alloc((size_t)256 * MSG * 2);
  bf* QBUFB = (bf*)alloc((size_t)256 * QN * 2);
  // fp32
  float* HFA32 = (float*)alloc((size_t)256 * 1024 * 4);
  float* HFO32 = (float*)alloc((size_t)256 * 1024 * 4);
  float* HPI32 = (float*)alloc((size_t)256 * 1024 * 4);
  float* XBUF32 = (float*)alloc((size_t)256 * 1024 * 4);
  float* GI = (float*)alloc((size_t)256 * 3072 * 4);
  float* GH = (float*)alloc((size_t)256 * 3072 * 4);
  float* QV = (float*)alloc((size_t)256 * 1024 * 4);
  float* KK = (float*)alloc((size_t)768 * 1024 * 4);
  float* VV = (float*)alloc((size_t)768 * 8 * 4);
  float* NM = (float*)alloc((size_t)2048 * 4);

  auto cvt = [&](const float* src, int srcld, bf* dst, int N, int Kdst, int Kval, int Npad) {
    size_t total = ((size_t)Npad * Kdst) / 8;
    int blocks = (int)((total + 255) / 256);
    k_cvtw<<<blocks, 256, 0, stream>>>(src, srcld, dst, N, Kdst, Kval, Npad);
  };
  auto mm = [&](const bf* Aa, int lda, const bf* Ww, int ldw, const float* bias,
                float* C, int ldc, bf* Cb, int ldcb,
                int M, int Npad, int Nlim, int K, int act) {
    dim3 g(Npad / 64, M / 64, 1);
    int nsteps = K / 128;
    if (act) k_mfma<1, false><<<g, 256, 0, stream>>>(Aa, lda, Ww, ldw, bias, C, ldc, Cb, ldcb, Nlim, nsteps);
    else     k_mfma<0, false><<<g, 256, 0, stream>>>(Aa, lda, Ww, ldw, bias, C, ldc, Cb, ldcb, Nlim, nsteps);
  };

  // weight + input conversions
  cvt(pi_fc1_w, 2560, WPI1, 1024, 2560, 2560, 1024);
  cvt(pi_fc2_w, 1024, WPI2, 64, 1024, 1024, 64);
  cvt(fa_fc1_w, 512,  WFA1, 1024, 512, 512, 1024);
  cvt(fa_fc2_w, 1024, WFA2, 16320, 1024, 1024, 16320);
  cvt(fo_fc1_w, 16896, WFO1, 1024, 16896, 16896, 1024);
  cvt(fo_fc2_w, 1024, WFO2, 512, 1024, 1024, 512);
  cvt(am_qs_w, 2048, WQS, 1024, 2048, 2048, 1024);
  cvt(am_ks_w, 576, WKS, 1024, TAUP, 576, 1024);
  cvt(pi_wih, 1024, WPIIH, 3072, 1024, 1024, 3072);
  cvt(pi_whh, 1024, WPIHH, 3072, 1024, 1024, 3072);
  cvt(fa_wih, 1024, WFAIH, 3072, 1024, 1024, 3072);
  cvt(fa_whh, 1024, WFAHH, 3072, 1024, 1024, 3072);
  cvt(fo_wih, 1024, WFOIH, 3072, 1024, 1024, 3072);
  cvt(fo_whh, 1024, WFOHH, 3072, 1024, 1024, 3072);
  cvt(inputs + 1088, INW, MSGB, 256, 2048, 2048, 256);

  k_init_h<<<3072, 256, 0, stream>>>(hidden, HFA32, HFO32, HPI32, HFAB, HFOB, HPIB, HPI0B);
  k_init_taus<<<3 * TAUP, 256, 0, stream>>>(inputs, TAUSB);

  for (int t = 0; t < 2; ++t) {
    bf* taus_t = TAUSB + (size_t)t * 256 * TAUP;
    bf* taus_n = TAUSB + (size_t)(t + 1) * 256 * TAUP;
    // fa branch
    mm(taus_t, TAUP, WFA1, 512, fa_fc1_b, nullptr, 0, XBUFB, 1024, 256, 1024, 1024, 512, 1);
    mm(XBUFB, 1024, WFAIH, 1024, fa_bih, GI, 3072, nullptr, 0, 256, 3072, 3072, 1024, 0);
    mm(HFAB, 1024, WFAHH, 1024, fa_bhh, GH, 3072, nullptr, 0, 256, 3072, 3072, 1024, 0);
    k_gru<<<1024, 256, 0, stream>>>(GI, GH, HFA32, 1024, HFA32, 1024, HFAB);
    mm(HFAB, 1024, WFA2, 1024, fa_fc2_b, nullptr, 0, QBUFB, QN, 256, QN, QN, 1024, 0);
    // x2 = [scrambled softmax | a | o]
    k_x2_tail<<<576, 256, 0, stream>>>(taus_t, X2B);
    k_softmax_scatter<<<16320, 256, 0, stream>>>(QBUFB, X2B);
    // fo branch (split-K 12, atomic fp32)
    k_fill_bias<<<1024, 256, 0, stream>>>(XBUF32, fo_fc1_b);
    {
      dim3 g(1024 / 64, 256 / 64, 12);
      k_mfma<0, true><<<g, 256, 0, stream>>>(X2B, X2W, WFO1, X2W, nullptr,
                                             XBUF32, 1024, nullptr, 0, 1024, 11);
    }
    k_relu_cvt<<<1024, 256, 0, stream>>>(XBUF32, XBUFB);
    mm(XBUFB, 1024, WFOIH, 1024, fo_bih, GI, 3072, nullptr, 0, 256, 3072, 3072, 1024, 0);
    mm(HFOB, 1024, WFOHH, 1024, fo_bhh, GH, 3072, nullptr, 0, 256, 3072, 3072, 1024, 0);
    k_gru<<<1024, 256, 0, stream>>>(GI, GH, HFO32, 1024, HFO32, 1024, HFOB);
    mm(HFOB, 1024, WFO2, 1024, fo_fc2_b, nullptr, 0, taus_n, TAUP, 256, 512, 512, 1024, 0);
    // pi branch
    k_concat_pi_loop<<<2560, 256, 0, stream>>>(taus_t, MSGB, PIINB);
    mm(PIINB, PIW, WPI1, PIW, pi_fc1_b, nullptr, 0, XBUFB, 1024, 256, 1024, 1024, 2560, 1);
    mm(XBUFB, 1024, WPIIH, 1024, pi_bih, GI, 3072, nullptr, 0, 256, 3072, 3072, 1024, 0);
    mm(HPIB, 1024, WPIHH, 1024, pi_bhh, GH, 3072, nullptr, 0, 256, 3072, 3072, 1024, 0);
    k_gru<<<1024, 256, 0, stream>>>(GI, GH, HPI32, 1024, HPI32, 1024, HPIB);
    mm(HPIB, 1024, WPI2, 1024, pi_fc2_b, nullptr, 0, taus_n + OBS, TAUP, 256, 64, 64, 1024, 0);
  }

  // attention
  mm(MSGB, MSG, WQS, MSG, am_qs_b, QV, 1024, nullptr, 0, 256, 1024, 1024, 2048, 0);
  mm(TAUSB, TAUP, WKS, TAUP, am_ks_b, KK, 1024, nullptr, 0, 768, 1024, 1024, TAUP, 0);
  k_vv<<<768, 64, 0, stream>>>(TAUSB, am_vs_w, am_vs_b, VV);
  k_attn<<<256, 64, 0, stream>>>(QV, KK, VV, NM, out);

  // final pi with original h_pi0
  k_concat_pi_final<<<2560, 256, 0, stream>>>(inputs, NM, PIINB);
  mm(PIINB, PIW, WPI1, PIW, pi_fc1_b, nullptr, 0, XBUFB, 1024, 256, 1024, 1024, 2560, 1);
  mm(XBUFB, 1024, WPIIH, 1024, pi_bih, GI, 3072, nullptr, 0, 256, 3072, 3072, 1024, 0);
  mm(HPI0B, 1024, WPIHH, 1024, pi_bhh, GH, 3072, nullptr, 0, 256, 3072, 3072, 1024, 0);
  k_gru<<<1024, 256, 0, stream>>>(GI, GH, hidden + 2048, 3072,
                                  out + 256 * 72 + 2048, 3072, HPIB);
  mm(HPIB, 1024, WPI2, 1024, pi_fc2_b, out + 8, 72, nullptr, 0, 256, 64, 64, 1024, 0);
  k_copy_hout<<<2048, 256, 0, stream>>>(HFA32, HFO32, out + 256 * 72);
  (void)in_sizes; (void)n_in; (void)out_size; (void)ws_size;
}